// Round 4
// baseline (597.724 us; speedup 1.0000x reference)
//
#include <hip/hip_runtime.h>
#include <hip/hip_bf16.h>

// PConvLinear: B=2, N=60000, K=16, C_in=64, C_add=3, C_mid=16.
// pconv[p][c][m] = sum_k feat[p][k][c] * Wn[p][k][m]   (c in 0..66)
// out[p][o]     = sum_f pconv_flat[p][f] * LW[o][f] + bias[o],  f = c*16+m, F=1072
#define NPTS  60000
#define NBLK  3750          // blocks per batch (16 points each)
#define FP    1088          // F padded to 34*32 for K-chunking
#define PSTR  1096          // sP row stride (f16): 548 dw, %32=4 -> 2-way (free)
#define KSTR  20            // sT row stride (f16): 40 B -> 8B-aligned b64 reads

typedef _Float16 f16x8 __attribute__((ext_vector_type(8)));
typedef _Float16 f16x4 __attribute__((ext_vector_type(4)));
typedef float    f32x4 __attribute__((ext_vector_type(4)));

// ---- pre-kernel: linear_weight fp32 [128][1072] -> f16 [128][1088] in d_ws ----
__global__ void __launch_bounds__(256)
cvt_lw_kernel(const float* __restrict__ LW, _Float16* __restrict__ LWh) {
    const int o = blockIdx.x;
    for (int f = threadIdx.x; f < FP; f += 256)
        LWh[o * FP + f] = (f < 1072) ? (_Float16)LW[o * 1072 + f] : (_Float16)0.f;
}

__global__ void __launch_bounds__(256, 4)
pconv_linear_mfma(const float* __restrict__ inF,   // [2][60000][64]
                  const int*   __restrict__ inds,  // [2][60000][16]
                  const float* __restrict__ Wn,    // [2][60000][16][16]
                  const float* __restrict__ addF,  // [2][60000][16][3]
                  const _Float16* __restrict__ LWh,// [128][1088] f16 (d_ws)
                  const float* __restrict__ bias,  // [128]
                  float*       __restrict__ out)   // [2][60000][128]
{
    __shared__ __align__(16) _Float16 sP[16 * PSTR];       // pconv tile [p][f]
    __shared__ __align__(16) _Float16 sT[4][32 * KSTR];    // per-wave gather tile [c'][k]

    const int t    = threadIdx.x;
    const int lane = t & 63;
    const int w    = t >> 6;        // wave 0..3
    const int q    = lane >> 4;     // quad 0..3
    const int ml   = lane & 15;
    const bool qlo = (q < 2);       // quads 0,1 carry the real K=16; 2,3 zero-pad

    const int bid = blockIdx.x;
    const int b   = bid / NBLK;
    const int n0  = (bid - b * NBLK) * 16;
    const int bN  = b * NPTS;

    const f32x4 z4 = {0.f, 0.f, 0.f, 0.f};

    // ---- (1) inds first: everything gather-side depends on it ----
    const int ind_lane = inds[(bN + n0 + w * 4) * 16 + lane];

    // ---- (2) Wn prefetch for point 0 (independent of inds, overlaps its latency) ----
    float wnb[2][8];
    {
        const int base0 = (bN + n0 + w * 4) * 16;
        #pragma unroll
        for (int j = 0; j < 8; ++j)
            wnb[0][j] = qlo ? Wn[(base0 + q * 8 + j) * 16 + ml] : 0.f;
    }

    // ---- (3) all 16 gather loads issued up front, consumed in issue order ----
    const int k0  = (lane >> 3) * 2;   // even row pair this lane gathers
    const int seg = lane & 7;          // 4-float segment within the 32-c half
    int idx[4][2];
    #pragma unroll
    for (int i = 0; i < 4; ++i) {
        idx[i][0] = __shfl(ind_lane, i * 16 + k0,     64);
        idx[i][1] = __shfl(ind_lane, i * 16 + k0 + 1, 64);
    }
    float4 g[4][2][2];   // [point][c-half][row]
    #pragma unroll
    for (int i = 0; i < 4; ++i) {
        #pragma unroll
        for (int ch = 0; ch < 2; ++ch) {
            g[i][ch][0] = *(const float4*)(inF + (bN + idx[i][0]) * 64 + ch * 32 + seg * 4);
            g[i][ch][1] = *(const float4*)(inF + (bN + idx[i][1]) * 64 + ch * 32 + seg * 4);
        }
    }

    _Float16* T = &sT[w][0];

    // ================= Phase A: pconv via MFMA =================
    // D[c_off][m] = A[c_off][k] * B[k][m]; A[row=ml][k=q*8+j] = feat[k][c],
    // B[col=ml][k=q*8+j] = Wn[k][ml]; D row = q*4+r, col = ml.
    for (int i = 0; i < 4; ++i) {
        const int p = w * 4 + i;
        const int base_nk = (bN + n0 + p) * 16;

        // rolling prefetch: next point's Wn fragment
        if (i < 3) {
            const int basen = (bN + n0 + p + 1) * 16;
            #pragma unroll
            for (int j = 0; j < 8; ++j)
                wnb[(i + 1) & 1][j] = qlo ? Wn[(basen + q * 8 + j) * 16 + ml] : 0.f;
        }
        // this point's addF (consumed last in the point -> latency hidden)
        float afv[8];
        #pragma unroll
        for (int j = 0; j < 8; ++j)
            afv[j] = (qlo && ml < 3) ? addF[(base_nk + q * 8 + j) * 3 + ml] : 0.f;

        f16x8 bf;
        #pragma unroll
        for (int j = 0; j < 8; ++j) bf[j] = (_Float16)wnb[i & 1][j];

        #pragma unroll
        for (int ch = 0; ch < 2; ++ch) {      // two 32-channel halves of c=0..63
            // pack rows (k0, k0+1) -> conflict-free ds_write_b32 into T[c'][k]
            {
                const float4 v0 = g[i][ch][0];
                const float4 v1 = g[i][ch][1];
                const float a0[4] = {v0.x, v0.y, v0.z, v0.w};
                const float a1[4] = {v1.x, v1.y, v1.z, v1.w};
                #pragma unroll
                for (int cc = 0; cc < 4; ++cc) {
                    union { _Float16 h[2]; unsigned u; } pk;
                    pk.h[0] = (_Float16)a0[cc];
                    pk.h[1] = (_Float16)a1[cc];
                    *(unsigned*)&T[(seg * 4 + cc) * KSTR + k0] = pk.u;
                }
            }
            // consume: 2 c-tiles; A[row=ml][k=q*8+j] = T[c'=h*16+ml][k]
            #pragma unroll
            for (int h = 0; h < 2; ++h) {
                f16x8 a = {0,0,0,0,0,0,0,0};
                if (qlo) {
                    const _Float16* ap = T + (h * 16 + ml) * KSTR + q * 8;
                    const f16x4 alo = *(const f16x4*)ap;        // ds_read_b64
                    const f16x4 ahi = *(const f16x4*)(ap + 4);
                    a[0]=alo[0]; a[1]=alo[1]; a[2]=alo[2]; a[3]=alo[3];
                    a[4]=ahi[0]; a[5]=ahi[1]; a[6]=ahi[2]; a[7]=ahi[3];
                }
                const f32x4 d = __builtin_amdgcn_mfma_f32_16x16x32_f16(a, bf, z4, 0, 0, 0);
                const int ct = ch * 2 + h;
                #pragma unroll
                for (int r = 0; r < 4; ++r)
                    sP[p * PSTR + (ct * 16 + q * 4 + r) * 16 + ml] = (_Float16)d[r];
            }
        }

        // c-tile 4: c=64..66 from addF; D rows 67+ zero -> f[1072,1088) pad
        {
            f16x8 afr;
            #pragma unroll
            for (int j = 0; j < 8; ++j) afr[j] = (_Float16)afv[j];
            const f32x4 d = __builtin_amdgcn_mfma_f32_16x16x32_f16(afr, bf, z4, 0, 0, 0);
            if (q == 0) {
                #pragma unroll
                for (int r = 0; r < 4; ++r)
                    sP[p * PSTR + (64 + r) * 16 + ml] = (_Float16)d[r];
            }
        }
    }
    __syncthreads();

    // ================= Phase B: out[16 x 128] = sP @ LWh^T ====================
    // Wave w owns o-tiles {w*32, w*32+16}. Split accumulators (2 chains each),
    // unroll x4 so ~4 iterations of L2 loads are in flight.
    const int o0 = w * 32;
    f32x4 acc0a = z4, acc0b = z4, acc1a = z4, acc1b = z4;
    const _Float16* aP  = sP + ml * PSTR + q * 8;
    const _Float16* bP0 = LWh + (o0 + ml) * FP + q * 8;
    const _Float16* bP1 = bP0 + 16 * FP;

    #pragma unroll 4
    for (int ch2 = 0; ch2 < 17; ++ch2) {     // 2 K-chunks per iteration
        const int c0 = ch2 * 64;
        f16x8 a0  = *(const f16x8*)(aP  + c0);        // ds_read_b128
        f16x8 a1  = *(const f16x8*)(aP  + c0 + 32);
        f16x8 b00 = *(const f16x8*)(bP0 + c0);        // global dwordx4, L2-resident
        f16x8 b01 = *(const f16x8*)(bP0 + c0 + 32);
        f16x8 b10 = *(const f16x8*)(bP1 + c0);
        f16x8 b11 = *(const f16x8*)(bP1 + c0 + 32);
        acc0a = __builtin_amdgcn_mfma_f32_16x16x32_f16(a0, b00, acc0a, 0, 0, 0);
        acc1a = __builtin_amdgcn_mfma_f32_16x16x32_f16(a0, b10, acc1a, 0, 0, 0);
        acc0b = __builtin_amdgcn_mfma_f32_16x16x32_f16(a1, b01, acc0b, 0, 0, 0);
        acc1b = __builtin_amdgcn_mfma_f32_16x16x32_f16(a1, b11, acc1b, 0, 0, 0);
    }
    const f32x4 acc0 = acc0a + acc0b;
    const f32x4 acc1 = acc1a + acc1b;

    // ================= Epilogue: bias + store (rows p=q*4+r, cols o0+ml / +16) ===
    const float bz0 = bias[o0 + ml];
    const float bz1 = bias[o0 + 16 + ml];
    float* obase = out + (bN + n0 + q * 4) * 128;
    #pragma unroll
    for (int r = 0; r < 4; ++r) {
        obase[r * 128 + o0 + ml]      = acc0[r] + bz0;
        obase[r * 128 + o0 + 16 + ml] = acc1[r] + bz1;
    }
}

extern "C" void kernel_launch(void* const* d_in, const int* in_sizes, int n_in,
                              void* d_out, int out_size, void* d_ws, size_t ws_size,
                              hipStream_t stream)
{
    const float* inF  = (const float*)d_in[0];
    const int*   inds = (const int*)  d_in[1];
    const float* Wn   = (const float*)d_in[2];
    const float* addF = (const float*)d_in[3];
    const float* LW   = (const float*)d_in[4];
    const float* bias = (const float*)d_in[5];
    float* out = (float*)d_out;
    _Float16* LWh = (_Float16*)d_ws;    // 278,528 B of scratch

    cvt_lw_kernel<<<dim3(128), dim3(256), 0, stream>>>(LW, LWh);
    pconv_linear_mfma<<<dim3(2 * NBLK), dim3(256), 0, stream>>>(
        inF, inds, Wn, addF, LWh, bias, out);
}